// Round 2
// baseline (6413.988 us; speedup 1.0000x reference)
//
#include <hip/hip_runtime.h>

#define K_CLUSTERS 512
#define FDIM 64
#define RPB 512      // rows per block; grid = N/RPB = 256 (1 block/CU, LDS-bound)
#define RT 4         // rows per wave-tile
#define NTILES 8     // tiles per wave: RPB / (16 waves * RT)

typedef float vf4 __attribute__((ext_vector_type(4)));

// Transpose W [F=64][K=512] -> Wt [K][F] (for epilogue gather), wsq[k].
// UNCHANGED (absmax 0.0 proven).
__global__ __launch_bounds__(64) void vq_prep(const float* __restrict__ W,
                                              float* __restrict__ Wt,
                                              float* __restrict__ wsq) {
    int k = blockIdx.x;
    int f = threadIdx.x;
    float w = W[f * K_CLUSTERS + k];
    Wt[k * FDIM + f] = w;
    float s = w * w;
#pragma unroll
    for (int off = 32; off > 0; off >>= 1) s += __shfl_xor(s, off, 64);
    if (f == 0) wsq[k] = s;
}

// Fused argmin + zq + diff + one-hot.
// Structure: full W lives in LDS (128 KB, XOR-swizzled so per-lane cluster-row
// ds_read_b128 is conflict-free); 1024-thread blocks give 16 waves/CU (50%
// occupancy); each wave independently owns 32 rows (8 tiles of 4 rows x all
// 512 clusters, 2 passes of 4 clusters/lane) -> no barriers after staging,
// no giant VGPR arrays for the compiler to rematerialize (the VGPR_Count=84
// failure mode of the previous structure).
// All arithmetic chains bit-identical to the proven kernel (absmax 0.0):
// ascending-f fmaf dot; fmaf(-2,dot,s)+wsq; 8-acc pairwise sumz; contract-off
// epilogue; lex-min (d,k) == np.argmin first-index rule.
__global__ __launch_bounds__(1024, 4) void vq_fused(const float* __restrict__ z,
                                                    const float* __restrict__ W,
                                                    const float* __restrict__ Wt,
                                                    const float* __restrict__ wsq,
                                                    float* __restrict__ out_zq,
                                                    float* __restrict__ out_idx,
                                                    float* __restrict__ enc,
                                                    float* __restrict__ out_diff) {
    // sW4[c*16 + (f4 ^ (c&15))] = W[4*f4..4*f4+3][c]  (16B-chunk XOR swizzle)
    __shared__ vf4 sW4[K_CLUSTERS * 16];   // 128 KB
    __shared__ vf4 sZ4[16 * RT * 16];      // 16 KB: per-wave 4-row z tiles

    const int tid = threadIdx.x;
    const int w = tid >> 6;
    const int l = tid & 63;
    const int xr = l & 15;

    // ---- Stage W into LDS (coalesced vf4 reads, swizzled scalar writes) ----
    {
        float* sWf = (float*)sW4;
        const vf4* Wg4 = (const vf4*)W;
#pragma unroll
        for (int it = 0; it < 8; it++) {
            int u4 = it * 1024 + tid;       // vf4 index over W (8192 total)
            vf4 v = Wg4[u4];
            int u = u4 << 2;                // float index; 4 elems same f, c0..c0+3
            int f = u >> 9;
            int c0 = u & 511;
            int f4 = f >> 2, m = f & 3;
#pragma unroll
            for (int e = 0; e < 4; e++) {
                int c = c0 + e;
                sWf[c * 64 + (((f4 ^ (c & 15)) << 2) + m)] = v[e];
            }
        }
    }
    __syncthreads();  // the only barrier in the kernel

    const int rowW = blockIdx.x * RPB + w * (RT * NTILES);
    vf4* sZw = sZ4 + w * (RT * 16);        // wave-private; no cross-wave sync needed
    const vf4* zg4 = (const vf4*)z;

    // prefetch first z tile (4 rows = 64 vf4, one per lane, coalesced)
    vf4 zv = zg4[(size_t)rowW * 16 + l];

#pragma unroll 1
    for (int t = 0; t < NTILES; t++) {
        const int row0 = rowW + t * RT;
        sZw[l] = zv;
        // prefetch next tile's z early (HBM latency hides under this tile's compute)
        int pre = (t < NTILES - 1) ? (row0 + RT) : row0;
        vf4 zn = zg4[(size_t)pre * 16 + l];

        // ---- sumz: exact numpy pairwise chain, lanes 0..3 (one row each) ----
        float sres = 0.0f;
        if (l < RT) {
            const float* zr = (const float*)(sZw + l * 16);
            {
#pragma clang fp contract(off)
                float r0 = zr[0] * zr[0], r1 = zr[1] * zr[1], r2 = zr[2] * zr[2], r3 = zr[3] * zr[3];
                float r4 = zr[4] * zr[4], r5 = zr[5] * zr[5], r6 = zr[6] * zr[6], r7 = zr[7] * zr[7];
#pragma unroll
                for (int b = 8; b < 64; b += 8) {
                    r0 += zr[b + 0] * zr[b + 0]; r1 += zr[b + 1] * zr[b + 1];
                    r2 += zr[b + 2] * zr[b + 2]; r3 += zr[b + 3] * zr[b + 3];
                    r4 += zr[b + 4] * zr[b + 4]; r5 += zr[b + 5] * zr[b + 5];
                    r6 += zr[b + 6] * zr[b + 6]; r7 += zr[b + 7] * zr[b + 7];
                }
                sres = ((r0 + r1) + (r2 + r3)) + ((r4 + r5) + (r6 + r7));
            }
        }
        float sA[RT];
        sA[0] = __shfl(sres, 0, 64);
        sA[1] = __shfl(sres, 1, 64);
        sA[2] = __shfl(sres, 2, 64);
        sA[3] = __shfl(sres, 3, 64);

        float bd[RT];
        int bk[RT];
#pragma unroll
        for (int r = 0; r < RT; r++) { bd[r] = INFINITY; bk[r] = 0; }

        // ---- two passes over clusters: lane l owns c = pass*256 + jj*64 + l ----
#pragma unroll 1
        for (int pass = 0; pass < 2; pass++) {
            const int cBase = (pass << 8) + l;
            float q[4];
#pragma unroll
            for (int jj = 0; jj < 4; jj++) q[jj] = wsq[cBase + (jj << 6)];
            float acc[RT][4];
#pragma unroll
            for (int r = 0; r < RT; r++)
#pragma unroll
                for (int jj = 0; jj < 4; jj++) acc[r][jj] = 0.0f;
            const vf4* wB = sW4 + ((size_t)cBase << 4);
#pragma unroll
            for (int f4 = 0; f4 < 16; f4++) {
                const int sl = f4 ^ xr;  // swizzled chunk; c&15 == l&15 for all jj
                vf4 zb[RT];              // wave-uniform broadcasts
                zb[0] = sZw[f4];
                zb[1] = sZw[16 + f4];
                zb[2] = sZw[32 + f4];
                zb[3] = sZw[48 + f4];
                vf4 wv[4];               // jj stride = 64 rows = 16384 B (imm offset)
                wv[0] = wB[sl];
                wv[1] = wB[1024 + sl];
                wv[2] = wB[2048 + sl];
                wv[3] = wB[3072 + sl];
#pragma unroll
                for (int r = 0; r < RT; r++)
#pragma unroll
                    for (int jj = 0; jj < 4; jj++) {
                        float a = acc[r][jj];
                        a = fmaf(zb[r].x, wv[jj].x, a);
                        a = fmaf(zb[r].y, wv[jj].y, a);
                        a = fmaf(zb[r].z, wv[jj].z, a);
                        a = fmaf(zb[r].w, wv[jj].w, a);
                        acc[r][jj] = a;
                    }
            }
            // distances + thread-local lex-min (ascending c within lane)
#pragma unroll
            for (int r = 0; r < RT; r++)
#pragma unroll
                for (int jj = 0; jj < 4; jj++) {
                    float d = fmaf(-2.0f, acc[r][jj], sA[r]) + q[jj];
                    int c = cBase + (jj << 6);
                    if (d < bd[r] || (d == bd[r] && c < bk[r])) { bd[r] = d; bk[r] = c; }
                }
        }

        // ---- 64-lane butterfly lex-min; 4 independent row-chains interleave ----
#pragma unroll
        for (int off = 1; off < 64; off <<= 1) {
#pragma unroll
            for (int r = 0; r < RT; r++) {
                float od = __shfl_xor(bd[r], off, 64);
                int ok = __shfl_xor(bk[r], off, 64);
                if (od < bd[r] || (od == bd[r] && ok < bk[r])) { bd[r] = od; bk[r] = ok; }
            }
        }
        // all lanes now hold the final (bd,bk) for all 4 rows

        if (l == 0) {
            out_idx[row0 + 0] = (float)bk[0];
            out_idx[row0 + 1] = (float)bk[1];
            out_idx[row0 + 2] = (float)bk[2];
            out_idx[row0 + 3] = (float)bk[3];
        }

        // ---- zq & diff (z from LDS, w gather from global Wt; bit-exact) ----
        {
            const int r = l >> 4, ch = l & 15;
            int kk = bk[0];
            if (r == 1) kk = bk[1];
            if (r == 2) kk = bk[2];
            if (r == 3) kk = bk[3];
            vf4 zvv = sZw[(r << 4) + ch];
            vf4 wvv = ((const vf4*)Wt)[((size_t)kk << 4) + ch];
            vf4 zq, df;
            {
#pragma clang fp contract(off)
                vf4 d1 = wvv - zvv;
                zq = zvv + d1;
                df = d1 * d1;
            }
            ((vf4*)out_zq)[(size_t)row0 * 16 + l] = zq;
            ((vf4*)out_diff)[(size_t)row0 * 16 + l] = df;
        }

        // ---- one-hot: coalesced plain stores, 8 x 1KB per wave-tile ----
        {
            vf4* enc4 = (vf4*)enc + (size_t)row0 * 128;
#pragma unroll
            for (int jj = 0; jj < 8; jj++) {
                const int row = jj >> 1;     // compile-time per unrolled jj
                int kk = bk[row];
                int c = kk - ((l + ((jj & 1) << 6)) << 2);
                vf4 v;
                v.x = (c == 0) ? 1.0f : 0.0f;
                v.y = (c == 1) ? 1.0f : 0.0f;
                v.z = (c == 2) ? 1.0f : 0.0f;
                v.w = (c == 3) ? 1.0f : 0.0f;
                enc4[(jj << 6) + l] = v;
            }
        }

        zv = zn;
    }
}

extern "C" void kernel_launch(void* const* d_in, const int* in_sizes, int n_in,
                              void* d_out, int out_size, void* d_ws, size_t ws_size,
                              hipStream_t stream) {
    const float* z = (const float*)d_in[0];
    const float* W = (const float*)d_in[1];
    int N = in_sizes[0] / FDIM;  // 131072

    float* out = (float*)d_out;
    float* out_zq = out;
    float* out_idx = out_zq + (size_t)N * FDIM;
    float* enc = out_idx + N;
    float* out_diff = enc + (size_t)N * K_CLUSTERS;

    float* Wt = (float*)d_ws;
    float* wsq = Wt + K_CLUSTERS * FDIM;

    vq_prep<<<K_CLUSTERS, 64, 0, stream>>>(W, Wt, wsq);
    vq_fused<<<N / RPB, 1024, 0, stream>>>(z, W, Wt, wsq, out_zq, out_idx, enc, out_diff);
}

// Round 3
// 727.188 us; speedup vs baseline: 8.8203x; 8.8203x over previous
//
#include <hip/hip_runtime.h>

#define K_CLUSTERS 512
#define FDIM 64
#define RPB 512      // rows per block; grid = N/RPB = 256 (1 block/CU, LDS-bound)
#define RT 8         // rows per wave-tile
#define NTILES 4     // tiles per wave: RPB / (16 waves * RT)

typedef float vf4 __attribute__((ext_vector_type(4)));

// Transpose W [F=64][K=512] -> Wt [K][F] (for epilogue gather), wsq[k].
// UNCHANGED (absmax 0.0 proven).
__global__ __launch_bounds__(64) void vq_prep(const float* __restrict__ W,
                                              float* __restrict__ Wt,
                                              float* __restrict__ wsq) {
    int k = blockIdx.x;
    int f = threadIdx.x;
    float w = W[f * K_CLUSTERS + k];
    Wt[k * FDIM + f] = w;
    float s = w * w;
#pragma unroll
    for (int off = 32; off > 0; off >>= 1) s += __shfl_xor(s, off, 64);
    if (f == 0) wsq[k] = s;
}

// Fused argmin + zq + diff + one-hot.
// W in LDS (128 KB, XOR-swizzled -> 2-way-max bank aliasing on ds_read_b128,
// which is free). z broadcasts come straight from global (wave-uniform addr ->
// single L1/L2 transaction on the otherwise-idle VMEM pipe), so the LDS pipe
// serves only per-lane W reads: (512/RT)*128KB = 8 MB/CU ~= 41 us. VALU floor
// ~= 62 us. 1024-thread blocks = 16 waves/CU; NO second launch_bounds arg
// (round 2: (1024,4) made the compiler cap VGPR at 64 -> 20 GB scratch spill).
// Block size alone forces VGPR <= 128; working set ~110.
// All arithmetic chains bit-identical to the proven kernel (absmax 0.0):
// ascending-f fmaf dot; fmaf(-2,dot,s)+wsq; 8-acc pairwise sumz (8 lanes/row,
// shfl_xor tree == exact pairwise tree); contract-off epilogue; lex-min (d,k)
// == np.argmin first-index rule.
__global__ __launch_bounds__(1024) void vq_fused(const float* __restrict__ z,
                                                 const float* __restrict__ W,
                                                 const float* __restrict__ Wt,
                                                 const float* __restrict__ wsq,
                                                 float* __restrict__ out_zq,
                                                 float* __restrict__ out_idx,
                                                 float* __restrict__ enc,
                                                 float* __restrict__ out_diff) {
    // sW4[c*16 + (f4 ^ (c&15))] = W[4*f4..4*f4+3][c]  (16B-chunk XOR swizzle)
    __shared__ vf4 sW4[K_CLUSTERS * 16];   // 128 KB, the only LDS

    const int tid = threadIdx.x;
    const int w = tid >> 6;
    const int l = tid & 63;
    const int xr = l & 15;

    // ---- Stage W into LDS (coalesced vf4 reads, swizzled scalar writes) ----
    {
        float* sWf = (float*)sW4;
        const vf4* Wg4 = (const vf4*)W;
#pragma unroll
        for (int it = 0; it < 8; it++) {
            int u4 = it * 1024 + tid;       // vf4 index over W (8192 total)
            vf4 v = Wg4[u4];
            int u = u4 << 2;                // float index; 4 elems same f, c0..c0+3
            int f = u >> 9;
            int c0 = u & 511;
            int f4 = f >> 2, m = f & 3;
#pragma unroll
            for (int e = 0; e < 4; e++) {
                int c = c0 + e;
                sWf[c * 64 + (((f4 ^ (c & 15)) << 2) + m)] = v[e];
            }
        }
    }
    __syncthreads();  // the only barrier in the kernel

    const int rowW = blockIdx.x * RPB + w * (RT * NTILES);
    const vf4* zg4 = (const vf4*)z;

#pragma unroll 1
    for (int t = 0; t < NTILES; t++) {
        const int row0 = rowW + t * RT;

        // ---- sumz: 8 lanes per row, one exact accumulator chain per lane ----
        // rj = zr[j]^2; rj += zr[8+j]^2; ... (ascending b, mul+add, no fma)
        // then shfl_xor tree (1,2,4) == ((r0+r1)+(r2+r3))+((r4+r5)+(r6+r7)).
        float srow;
        {
            const float* zr = z + (size_t)(row0 + (l >> 3)) * FDIM;
            const int j = l & 7;
            float rj;
            {
#pragma clang fp contract(off)
                rj = zr[j] * zr[j];
#pragma unroll
                for (int b = 8; b < 64; b += 8) rj += zr[b + j] * zr[b + j];
            }
            float s01 = rj + __shfl_xor(rj, 1, 64);
            float s03 = s01 + __shfl_xor(s01, 2, 64);
            srow = s03 + __shfl_xor(s03, 4, 64);
        }
        float sA[RT];
#pragma unroll
        for (int r = 0; r < RT; r++) sA[r] = __shfl(srow, r << 3, 64);

        float bd[RT];
        int bk[RT];
#pragma unroll
        for (int r = 0; r < RT; r++) { bd[r] = INFINITY; bk[r] = 0; }

        const vf4* zt = zg4 + (size_t)row0 * 16;  // wave-uniform z tile base

        // ---- two passes over clusters: lane l owns c = pass*256 + jj*64 + l ----
#pragma unroll 1
        for (int pass = 0; pass < 2; pass++) {
            const int cBase = (pass << 8) + l;
            float q0 = wsq[cBase];
            float q1 = wsq[cBase + 64];
            float q2 = wsq[cBase + 128];
            float q3 = wsq[cBase + 192];
            float acc[RT][4];
#pragma unroll
            for (int r = 0; r < RT; r++)
#pragma unroll
                for (int jj = 0; jj < 4; jj++) acc[r][jj] = 0.0f;
            const vf4* wB = sW4 + ((size_t)cBase << 4);
#pragma unroll 4
            for (int f4 = 0; f4 < 16; f4++) {
                const int sl = f4 ^ xr;  // swizzled chunk; c&15 == l&15 for all jj
                vf4 wv0 = wB[sl];                 // jj stride = 64 rows = 16 KB
                vf4 wv1 = wB[1024 + sl];
                vf4 wv2 = wB[2048 + sl];
                vf4 wv3 = wB[3072 + sl];
#pragma unroll
                for (int r = 0; r < RT; r++) {
                    vf4 zb = zt[(r << 4) + f4];   // uniform addr -> L1 broadcast
                    float a0 = acc[r][0], a1 = acc[r][1], a2 = acc[r][2], a3 = acc[r][3];
                    a0 = fmaf(zb.x, wv0.x, a0); a1 = fmaf(zb.x, wv1.x, a1);
                    a2 = fmaf(zb.x, wv2.x, a2); a3 = fmaf(zb.x, wv3.x, a3);
                    a0 = fmaf(zb.y, wv0.y, a0); a1 = fmaf(zb.y, wv1.y, a1);
                    a2 = fmaf(zb.y, wv2.y, a2); a3 = fmaf(zb.y, wv3.y, a3);
                    a0 = fmaf(zb.z, wv0.z, a0); a1 = fmaf(zb.z, wv1.z, a1);
                    a2 = fmaf(zb.z, wv2.z, a2); a3 = fmaf(zb.z, wv3.z, a3);
                    a0 = fmaf(zb.w, wv0.w, a0); a1 = fmaf(zb.w, wv1.w, a1);
                    a2 = fmaf(zb.w, wv2.w, a2); a3 = fmaf(zb.w, wv3.w, a3);
                    acc[r][0] = a0; acc[r][1] = a1; acc[r][2] = a2; acc[r][3] = a3;
                }
            }
            // distances + thread-local lex-min (ascending c within lane)
#pragma unroll
            for (int r = 0; r < RT; r++) {
                float d0 = fmaf(-2.0f, acc[r][0], sA[r]) + q0;
                float d1 = fmaf(-2.0f, acc[r][1], sA[r]) + q1;
                float d2 = fmaf(-2.0f, acc[r][2], sA[r]) + q2;
                float d3 = fmaf(-2.0f, acc[r][3], sA[r]) + q3;
                if (d0 < bd[r] || (d0 == bd[r] && cBase < bk[r])) { bd[r] = d0; bk[r] = cBase; }
                if (d1 < bd[r] || (d1 == bd[r] && cBase + 64 < bk[r])) { bd[r] = d1; bk[r] = cBase + 64; }
                if (d2 < bd[r] || (d2 == bd[r] && cBase + 128 < bk[r])) { bd[r] = d2; bk[r] = cBase + 128; }
                if (d3 < bd[r] || (d3 == bd[r] && cBase + 192 < bk[r])) { bd[r] = d3; bk[r] = cBase + 192; }
            }
        }

        // ---- 64-lane butterfly lex-min; 8 independent row-chains interleave ----
#pragma unroll
        for (int off = 1; off < 64; off <<= 1) {
#pragma unroll
            for (int r = 0; r < RT; r++) {
                float od = __shfl_xor(bd[r], off, 64);
                int ok = __shfl_xor(bk[r], off, 64);
                if (od < bd[r] || (od == bd[r] && ok < bk[r])) { bd[r] = od; bk[r] = ok; }
            }
        }
        // all lanes now hold the final (bd,bk) for all 8 rows

        if (l == 0) {
#pragma unroll
            for (int r = 0; r < RT; r++) out_idx[row0 + r] = (float)bk[r];
        }

        // ---- zq & diff (z re-read from L1/L2, w gather from Wt; bit-exact) ----
#pragma unroll
        for (int h = 0; h < 2; h++) {
            const int rsel = l >> 4;              // 0..3 within half
            int kk = bk[4 * h + 0];
            if (rsel == 1) kk = bk[4 * h + 1];
            if (rsel == 2) kk = bk[4 * h + 2];
            if (rsel == 3) kk = bk[4 * h + 3];
            vf4 zvv = zt[(h << 6) + l];           // == z[row0 + 4h + rsel][chunk]
            vf4 wvv = ((const vf4*)Wt)[((size_t)kk << 4) + (l & 15)];
            vf4 zq, df;
            {
#pragma clang fp contract(off)
                vf4 d1 = wvv - zvv;
                zq = zvv + d1;
                df = d1 * d1;
            }
            ((vf4*)out_zq)[(size_t)row0 * 16 + (h << 6) + l] = zq;
            ((vf4*)out_diff)[(size_t)row0 * 16 + (h << 6) + l] = df;
        }

        // ---- one-hot: coalesced plain stores, 16 x 1KB per wave-tile ----
        {
            vf4* enc4 = (vf4*)enc + (size_t)row0 * 128;
#pragma unroll
            for (int jj = 0; jj < 16; jj++) {
                const int row = jj >> 1;     // compile-time per unrolled jj
                int kk = bk[row];
                int c = kk - ((l + ((jj & 1) << 6)) << 2);
                vf4 v;
                v.x = (c == 0) ? 1.0f : 0.0f;
                v.y = (c == 1) ? 1.0f : 0.0f;
                v.z = (c == 2) ? 1.0f : 0.0f;
                v.w = (c == 3) ? 1.0f : 0.0f;
                enc4[(jj << 6) + l] = v;
            }
        }
    }
}

extern "C" void kernel_launch(void* const* d_in, const int* in_sizes, int n_in,
                              void* d_out, int out_size, void* d_ws, size_t ws_size,
                              hipStream_t stream) {
    const float* z = (const float*)d_in[0];
    const float* W = (const float*)d_in[1];
    int N = in_sizes[0] / FDIM;  // 131072

    float* out = (float*)d_out;
    float* out_zq = out;
    float* out_idx = out_zq + (size_t)N * FDIM;
    float* enc = out_idx + N;
    float* out_diff = enc + (size_t)N * K_CLUSTERS;

    float* Wt = (float*)d_ws;
    float* wsq = Wt + K_CLUSTERS * FDIM;

    vq_prep<<<K_CLUSTERS, 64, 0, stream>>>(W, Wt, wsq);
    vq_fused<<<N / RPB, 1024, 0, stream>>>(z, W, Wt, wsq, out_zq, out_idx, enc, out_diff);
}